// Round 15
// baseline (201.889 us; speedup 1.0000x reference)
//
#include <hip/hip_runtime.h>
#include <hip/hip_fp16.h>

// GCN layer: out = leaky_relu( segment_sum(edge_vals[:,None] * embeds[col], row, N), 0.5 )
// E = 3.2M, N = 100000, D = 128, f32 in/out.
//
// R17: best-of-both consolidation. Frame = R13 (179.8us proven): RPB=64
//   (1563 bins), bin-major hist[nbins][NBLK] (1.6MB, cheap), scanA+scanC,
//   1024-thread scatter, int4-vectorized loads, packed f32x2 FMA accumulate.
//   Plus R16's one compatible win: rank-fused single-read sort at CAP=1024
//   (2 entries/thread in regs -- VGPR-safe, unlike R9's 6/thread): count
//   pass captures rank=atomicAdd(&cnt[rl],1); place at offs[rl]+rank.
//   Removes one 25.6MB entry pass + cur[] from bin_reduce.
// Findings driving this: bin_reduce is gather-service-rate bound (~112us
//   across occupancy 69-79% -- R14/R16 proved occupancy is not the lever);
//   fine bins (RPB=16) cost +12us in "other" for -2us in bin_reduce.
// Established dead-ends (do not revisit): LDS FP atomics (atomicAdd R6,
// unsafeAtomicAdd R10 = CAS loops -> ~2.4ms); far-atomic chain builds
// (~165us cap, R2-R5); half-wave gathers (R8); 6-entry reg-staging (R9);
// NT loads in count/place (R12); fine-bin tables (R14-R16).
// Pipeline: hist(+fused f32->f16 convert) -> scanA -> scanC -> scatter -> bin_reduce.
// No global atomics, no FP atomics anywhere in the fast path.

#define GCN_D       128
#define LEAKY_SLOPE 0.5f
#define NBLK        256      // hist/scatter chunk partition of E
#define RPB         64       // rows per bin
#define RPB_SH      6
#define CAP         1024     // entries per rank-fused chunk (8 KB, 2/thread)
#define NBINS_MAX   2048
#define SCAN_G      512      // scan pass-A/C blocks
#define NCHAIN_FB   4

typedef int      i32x4 __attribute__((ext_vector_type(4)));
typedef float    f32x2 __attribute__((ext_vector_type(2)));
typedef float    f32x4 __attribute__((ext_vector_type(4)));
typedef unsigned u32x2 __attribute__((ext_vector_type(2)));
typedef unsigned u32x4 __attribute__((ext_vector_type(4)));

__device__ inline unsigned pack_half2(float a, float b) {
    __half2 h = __floats2half2_rn(a, b);
    return *reinterpret_cast<unsigned*>(&h);
}

__device__ inline f32x2 h2_to_f2(__half2 h) {
    float2 f = __half22float2(h);
    f32x2 r; r.x = f.x; r.y = f.y;
    return r;
}

// ---------------- Pass 1: histogram + fused f32->f16 conversion ----------------

__global__ void hist_convert_kernel(const int* __restrict__ row,
                                    int E, int CH, int nbins,
                                    unsigned* __restrict__ hist,   // [nbins][NBLK]
                                    const f32x4* __restrict__ emb4,
                                    int n8,
                                    u32x4* __restrict__ h8) {
    __shared__ unsigned h[NBINS_MAX];
    if ((int)blockIdx.x < NBLK) {
        int b = blockIdx.x;
        for (int i = threadIdx.x; i < nbins; i += blockDim.x) h[i] = 0u;
        __syncthreads();
        int s = b * CH;
        int e = min(E, s + CH);
        int n = e - s;
        int g4 = n >> 2;                       // CH=12500: s is 4-aligned
        const i32x4* row4 = reinterpret_cast<const i32x4*>(row + s);
        for (int g = threadIdx.x; g < g4; g += blockDim.x) {
            i32x4 r4 = row4[g];
            atomicAdd(&h[r4.x >> RPB_SH], 1u);
            atomicAdd(&h[r4.y >> RPB_SH], 1u);
            atomicAdd(&h[r4.z >> RPB_SH], 1u);
            atomicAdd(&h[r4.w >> RPB_SH], 1u);
        }
        for (int i = s + (g4 << 2) + threadIdx.x; i < e; i += blockDim.x)
            atomicAdd(&h[row[i] >> RPB_SH], 1u);
        __syncthreads();
        for (int i = threadIdx.x; i < nbins; i += blockDim.x)
            hist[(long long)i * NBLK + b] = h[i];
    } else {
        int bid = (int)blockIdx.x - NBLK;
        int nb  = (int)gridDim.x - NBLK;
        int stride = nb * blockDim.x;
        for (int i = bid * blockDim.x + threadIdx.x; i < n8; i += stride) {
            f32x4 a  = __builtin_nontemporal_load(&emb4[2 * i]);
            f32x4 b2 = __builtin_nontemporal_load(&emb4[2 * i + 1]);
            u32x4 o;
            o.x = pack_half2(a.x, a.y);
            o.y = pack_half2(a.z, a.w);
            o.z = pack_half2(b2.x, b2.y);
            o.w = pack_half2(b2.z, b2.w);
            h8[i] = o;   // cache-allocate: gathers want this resident
        }
    }
}

// ---------------- Pass 2: 2-kernel multi-block exclusive scan ----------------

__global__ void __launch_bounds__(256)
scanA_kernel(const unsigned* __restrict__ data, int M, int chunk,
             unsigned* __restrict__ bsum) {
    __shared__ unsigned red[256];
    int b = blockIdx.x, t = threadIdx.x;
    long long s = (long long)b * chunk;
    unsigned acc = 0;
    for (int i = t; i < chunk; i += 256) {
        long long j = s + i;
        if (j < M) acc += data[j];
    }
    red[t] = acc;
    __syncthreads();
    for (int off = 128; off > 0; off >>= 1) {
        if (t < off) red[t] += red[t + off];
        __syncthreads();
    }
    if (t == 0) bsum[b] = red[0];
}

// scanC also reduces bsum[0..b) itself (raw block sums; <=SCAN_G u32).
__global__ void __launch_bounds__(256)
scanC_kernel(unsigned* __restrict__ data, int M, int chunk,
             const unsigned* __restrict__ bsum) {
    __shared__ unsigned pre[256];
    __shared__ unsigned basev;
    int b = blockIdx.x, t = threadIdx.x;

    unsigned acc0 = 0;
    for (int i = t; i < b; i += 256) acc0 += bsum[i];
    pre[t] = acc0;
    __syncthreads();
    for (int off = 128; off > 0; off >>= 1) {
        if (t < off) pre[t] += pre[t + off];
        __syncthreads();
    }
    if (t == 0) basev = pre[0];
    __syncthreads();

    long long s0 = (long long)b * chunk;
    long long s1 = s0 + chunk;
    int ept = (chunk + 255) / 256;
    long long ts = s0 + (long long)t * ept;

    unsigned acc = 0;
    for (int i = 0; i < ept; ++i) {
        long long j = ts + i;
        if (j < s1 && j < M) acc += data[j];
    }
    __syncthreads();
    pre[t] = acc;
    __syncthreads();
    for (int off = 1; off < 256; off <<= 1) {
        unsigned u = (t >= off) ? pre[t - off] : 0u;
        __syncthreads();
        pre[t] += u;
        __syncthreads();
    }
    unsigned run = basev + ((t == 0) ? 0u : pre[t - 1]);
    for (int i = 0; i < ept; ++i) {
        long long j = ts + i;
        if (j < s1 && j < M) {
            unsigned v = data[j];
            data[j] = run;
            run += v;
        }
    }
}

// ---------------- Pass 3: scatter entries at deterministic offsets ----------------

__global__ void __launch_bounds__(1024)
scatter_kernel(const int* __restrict__ row,
               const int* __restrict__ col,
               const float* __restrict__ val,
               int E, int CH, int nbins,
               const unsigned* __restrict__ scanned, // [nbins][NBLK]
               u32x2* __restrict__ entry) {
    __shared__ unsigned cur[NBINS_MAX];
    int b = blockIdx.x;
    for (int i = threadIdx.x; i < nbins; i += blockDim.x)
        cur[i] = scanned[(long long)i * NBLK + b];
    __syncthreads();

    int s = b * CH;
    int e = min(E, s + CH);
    int n = e - s;
    int g4 = n >> 2;

    const i32x4* row4 = reinterpret_cast<const i32x4*>(row + s);
    const i32x4* col4 = reinterpret_cast<const i32x4*>(col + s);
    const f32x4* val4 = reinterpret_cast<const f32x4*>(val + s);

    for (int g = threadIdx.x; g < g4; g += 1024) {
        i32x4 r4 = row4[g];
        i32x4 c4 = col4[g];
        f32x4 v4 = val4[g];
        #pragma unroll
        for (int k = 0; k < 4; ++k) {
            int r = r4[k];
            unsigned key = ((unsigned)(r & (RPB - 1)) << 17) | (unsigned)c4[k];
            unsigned pos = atomicAdd(&cur[r >> RPB_SH], 1u); // native u32 LDS atomic
            u32x2 q; q.x = key; q.y = __float_as_uint(v4[k]);
            entry[pos] = q;  // plain store: let L2 merge partial lines
        }
    }
    for (int i = s + (g4 << 2) + threadIdx.x; i < e; i += 1024) {
        int r = row[i];
        unsigned key = ((unsigned)(r & (RPB - 1)) << 17) | (unsigned)col[i];
        unsigned pos = atomicAdd(&cur[r >> RPB_SH], 1u);
        u32x2 q; q.x = key; q.y = __float_as_uint(val[i]);
        entry[pos] = q;
    }
}

// ---------------- Pass 4: per-bin rank-fused counting sort + packed register reduce ----------------

__global__ void __launch_bounds__(512)
bin_reduce_kernel(const unsigned* __restrict__ scanned, // [nbins][NBLK]
                  const u32x2* __restrict__ entry,
                  const __half2* __restrict__ ebh,      // N*64 half2
                  float* __restrict__ out,
                  int E, int N, int nbins) {
    __shared__ u32x2    sorted[CAP];         // 8 KB
    __shared__ unsigned cnt[RPB];
    __shared__ unsigned offs[RPB];

    int b    = blockIdx.x;
    int tid  = threadIdx.x;
    int wave = tid >> 6;     // 0..7
    int lane = tid & 63;

    int seg0 = (int)scanned[(long long)b * NBLK];
    int seg1 = (b + 1 < nbins) ? (int)scanned[(long long)(b + 1) * NBLK] : E;

    f32x2 acc[8];
    #pragma unroll
    for (int j = 0; j < 8; ++j) { acc[j].x = 0.f; acc[j].y = 0.f; }

    for (int cs = seg0; cs < seg1; cs += CAP) {
        int n = min(CAP, seg1 - cs);

        if (tid < RPB) cnt[tid] = 0u;
        __syncthreads();

        // single global read: hold <=2 entries + ranks in registers
        u32x2 q0, q1;
        unsigned r0 = 0, r1 = 0;
        bool h0 = tid < n, h1 = tid + 512 < n;
        if (h0) {
            q0 = entry[cs + tid];
            r0 = atomicAdd(&cnt[q0.x >> 17], 1u);   // native u32 LDS atomic
        }
        if (h1) {
            q1 = entry[cs + tid + 512];
            r1 = atomicAdd(&cnt[q1.x >> 17], 1u);
        }
        __syncthreads();

        // wave-parallel 64-lane exclusive prefix over cnt (RPB == 64)
        if (wave == 0) {
            unsigned c = cnt[lane];
            unsigned s = c;
            #pragma unroll
            for (int off = 1; off < 64; off <<= 1) {
                unsigned t = __shfl_up(s, off, 64);
                if (lane >= off) s += t;
            }
            offs[lane] = s - c;
        }
        __syncthreads();

        // place from registers at offs[row] + rank (no re-read, no cur[])
        if (h0) sorted[offs[q0.x >> 17] + r0] = q0;
        if (h1) sorted[offs[q1.x >> 17] + r1] = q1;
        __syncthreads();

        // accumulate: each wave owns 8 rows; full-wave 256B gathers;
        // 8-deep main, 4-deep middle, 1-deep tail; packed f32x2 FMA.
        #pragma unroll
        for (int j = 0; j < 8; ++j) {
            int r  = (wave << 3) + j;
            int s  = (int)offs[r];
            int en = s + (int)cnt[r];
            int i  = s;
            for (; i + 8 <= en; i += 8) {
                u32x2 e0 = sorted[i],     e1 = sorted[i + 1];
                u32x2 e2 = sorted[i + 2], e3 = sorted[i + 3];
                u32x2 e4 = sorted[i + 4], e5 = sorted[i + 5];
                u32x2 e6 = sorted[i + 6], e7 = sorted[i + 7];
                __half2 m0 = ebh[(long long)(e0.x & 0x1FFFFu) * 64 + lane];
                __half2 m1 = ebh[(long long)(e1.x & 0x1FFFFu) * 64 + lane];
                __half2 m2 = ebh[(long long)(e2.x & 0x1FFFFu) * 64 + lane];
                __half2 m3 = ebh[(long long)(e3.x & 0x1FFFFu) * 64 + lane];
                __half2 m4 = ebh[(long long)(e4.x & 0x1FFFFu) * 64 + lane];
                __half2 m5 = ebh[(long long)(e5.x & 0x1FFFFu) * 64 + lane];
                __half2 m6 = ebh[(long long)(e6.x & 0x1FFFFu) * 64 + lane];
                __half2 m7 = ebh[(long long)(e7.x & 0x1FFFFu) * 64 + lane];
                f32x2 vv;
                vv.x = vv.y = __uint_as_float(e0.y); acc[j] += vv * h2_to_f2(m0);
                vv.x = vv.y = __uint_as_float(e1.y); acc[j] += vv * h2_to_f2(m1);
                vv.x = vv.y = __uint_as_float(e2.y); acc[j] += vv * h2_to_f2(m2);
                vv.x = vv.y = __uint_as_float(e3.y); acc[j] += vv * h2_to_f2(m3);
                vv.x = vv.y = __uint_as_float(e4.y); acc[j] += vv * h2_to_f2(m4);
                vv.x = vv.y = __uint_as_float(e5.y); acc[j] += vv * h2_to_f2(m5);
                vv.x = vv.y = __uint_as_float(e6.y); acc[j] += vv * h2_to_f2(m6);
                vv.x = vv.y = __uint_as_float(e7.y); acc[j] += vv * h2_to_f2(m7);
            }
            if (i + 4 <= en) {
                u32x2 e0 = sorted[i],     e1 = sorted[i + 1];
                u32x2 e2 = sorted[i + 2], e3 = sorted[i + 3];
                __half2 m0 = ebh[(long long)(e0.x & 0x1FFFFu) * 64 + lane];
                __half2 m1 = ebh[(long long)(e1.x & 0x1FFFFu) * 64 + lane];
                __half2 m2 = ebh[(long long)(e2.x & 0x1FFFFu) * 64 + lane];
                __half2 m3 = ebh[(long long)(e3.x & 0x1FFFFu) * 64 + lane];
                f32x2 vv;
                vv.x = vv.y = __uint_as_float(e0.y); acc[j] += vv * h2_to_f2(m0);
                vv.x = vv.y = __uint_as_float(e1.y); acc[j] += vv * h2_to_f2(m1);
                vv.x = vv.y = __uint_as_float(e2.y); acc[j] += vv * h2_to_f2(m2);
                vv.x = vv.y = __uint_as_float(e3.y); acc[j] += vv * h2_to_f2(m3);
                i += 4;
            }
            for (; i < en; ++i) {
                u32x2 qq = sorted[i];
                __half2 mm = ebh[(long long)(qq.x & 0x1FFFFu) * 64 + lane];
                f32x2 vv; vv.x = vv.y = __uint_as_float(qq.y);
                acc[j] += vv * h2_to_f2(mm);
            }
        }
        __syncthreads();
    }

    // fused leaky_relu + coalesced 512B stores (bin owns rows exclusively)
    int gr0 = b * RPB + (wave << 3);
    #pragma unroll
    for (int j = 0; j < 8; ++j) {
        int gr = gr0 + j;
        if (gr < N) {
            float x = acc[j].x, y = acc[j].y;
            x = x > 0.f ? x : LEAKY_SLOPE * x;
            y = y > 0.f ? y : LEAKY_SLOPE * y;
            f32x2 o; o.x = x; o.y = y;
            __builtin_nontemporal_store(
                o, reinterpret_cast<f32x2*>(out) + (long long)gr * 64 + lane);
        }
    }
}

// ---------------- R3 fallback: chains + f32 gather ----------------

__global__ void build_nodes_kernel(const int* __restrict__ row,
                                   const int* __restrict__ col,
                                   const float* __restrict__ val,
                                   int E,
                                   int* __restrict__ head,
                                   int4* __restrict__ node) {
    int stride = gridDim.x * blockDim.x;
    for (int i = blockIdx.x * blockDim.x + threadIdx.x; i < E; i += stride) {
        int   r = row[i];
        int   c = col[i];
        float v = val[i];
        int prev = atomicExch(&head[r * NCHAIN_FB + (i & (NCHAIN_FB - 1))], i);
        node[i] = make_int4(prev, c, __float_as_int(v), 0);
    }
}

__global__ void __launch_bounds__(256)
reduce_nodes_kernel(const int* __restrict__ head,
                    const int4* __restrict__ node,
                    const float* __restrict__ embeds,
                    float* __restrict__ out,
                    int N) {
    int wave = (int)((blockIdx.x * (long long)blockDim.x + threadIdx.x) >> 6);
    int lane = threadIdx.x & 63;
    if (wave >= N) return;

    const float2* eb = reinterpret_cast<const float2*>(embeds);
    int4 h = reinterpret_cast<const int4*>(head)[wave];
    int e0 = h.x, e1 = h.y, e2 = h.z, e3 = h.w;

    float ax = 0.f, ay = 0.f;

    while ((e0 & e1 & e2 & e3) != -1) {
        int i0 = e0 >= 0 ? e0 : 0;
        int i1 = e1 >= 0 ? e1 : 0;
        int i2 = e2 >= 0 ? e2 : 0;
        int i3 = e3 >= 0 ? e3 : 0;

        int4 n0 = node[i0];
        int4 n1 = node[i1];
        int4 n2 = node[i2];
        int4 n3 = node[i3];

        int c0 = e0 >= 0 ? n0.y : 0;
        int c1 = e1 >= 0 ? n1.y : 0;
        int c2 = e2 >= 0 ? n2.y : 0;
        int c3 = e3 >= 0 ? n3.y : 0;

        float2 m0 = eb[(long long)c0 * 64 + lane];
        float2 m1 = eb[(long long)c1 * 64 + lane];
        float2 m2 = eb[(long long)c2 * 64 + lane];
        float2 m3 = eb[(long long)c3 * 64 + lane];

        float v0 = e0 >= 0 ? __int_as_float(n0.z) : 0.f;
        float v1 = e1 >= 0 ? __int_as_float(n1.z) : 0.f;
        float v2 = e2 >= 0 ? __int_as_float(n2.z) : 0.f;
        float v3 = e3 >= 0 ? __int_as_float(n3.z) : 0.f;

        ax += v0 * m0.x; ay += v0 * m0.y;
        ax += v1 * m1.x; ay += v1 * m1.y;
        ax += v2 * m2.x; ay += v2 * m2.y;
        ax += v3 * m3.x; ay += v3 * m3.y;

        e0 = e0 >= 0 ? n0.x : -1;
        e1 = e1 >= 0 ? n1.x : -1;
        e2 = e2 >= 0 ? n2.x : -1;
        e3 = e3 >= 0 ? n3.x : -1;
    }

    ax = ax > 0.f ? ax : LEAKY_SLOPE * ax;
    ay = ay > 0.f ? ay : LEAKY_SLOPE * ay;
    reinterpret_cast<float2*>(out)[(long long)wave * 64 + lane] =
        make_float2(ax, ay);
}

// ---------------- R0 fallback: atomic scatter ----------------

__global__ void gcn_scatter_kernel(const int* __restrict__ row_idx,
                                   const int* __restrict__ col_idx,
                                   const float* __restrict__ vals,
                                   const float* __restrict__ embeds,
                                   float* __restrict__ out,
                                   int E) {
    long long tid = (long long)blockIdx.x * blockDim.x + threadIdx.x;
    long long e = tid >> 5;
    if (e >= E) return;
    int q = (int)(tid & 31);
    int row = row_idx[e];
    int col = col_idx[e];
    float v = vals[e];
    const float4* src =
        reinterpret_cast<const float4*>(embeds + (long long)col * GCN_D) + q;
    float4 m = *src;
    float* dst = out + (long long)row * GCN_D + (long long)q * 4;
    atomicAdd(dst + 0, v * m.x);
    atomicAdd(dst + 1, v * m.y);
    atomicAdd(dst + 2, v * m.z);
    atomicAdd(dst + 3, v * m.w);
}

__global__ void gcn_leaky_relu_kernel(float* __restrict__ out, int n4) {
    int i = blockIdx.x * blockDim.x + threadIdx.x;
    if (i >= n4) return;
    float4* p = reinterpret_cast<float4*>(out) + i;
    float4 x = *p;
    x.x = x.x > 0.f ? x.x : LEAKY_SLOPE * x.x;
    x.y = x.y > 0.f ? x.y : LEAKY_SLOPE * x.y;
    x.z = x.z > 0.f ? x.z : LEAKY_SLOPE * x.z;
    x.w = x.w > 0.f ? x.w : LEAKY_SLOPE * x.w;
    *p = x;
}

// ---------------------------------------------------------------------------

extern "C" void kernel_launch(void* const* d_in, const int* in_sizes, int n_in,
                              void* d_out, int out_size, void* d_ws, size_t ws_size,
                              hipStream_t stream) {
    const int*   edge_index = (const int*)d_in[0];   // (2, E) flat, int32
    const float* edge_vals  = (const float*)d_in[1]; // (E,)
    const float* embeds     = (const float*)d_in[2]; // (N, 128) f32
    float*       out        = (float*)d_out;         // (N, 128) f32

    const int E = in_sizes[1];
    const int N = out_size / GCN_D;                  // 100000
    const int* row = edge_index;
    const int* col = edge_index + E;

    const int block = 256;
    const int nbins = (N + RPB - 1) / RPB;           // 1563
    const int M     = nbins * NBLK;                  // 400128
    const int CH    = (E + NBLK - 1) / NBLK;         // 12500
    const int chunk = (M + SCAN_G - 1) / SCAN_G;     // 782

    // R17 ws layout: hist[M u32] | bsum[SCAN_G u32] | entry[E u32x2] | fp16 table
    size_t hist_b = (((size_t)M * sizeof(unsigned)) + 255) & ~(size_t)255;
    size_t bsum_b = (((size_t)SCAN_G * sizeof(unsigned)) + 255) & ~(size_t)255;
    size_t ent_b  = (((size_t)E * sizeof(u32x2)) + 255) & ~(size_t)255;
    size_t half_b = (size_t)N * GCN_D * sizeof(__half);
    size_t need_r17 = hist_b + bsum_b + ent_b + half_b;  // ~53 MB

    size_t head_fb = (size_t)N * NCHAIN_FB * sizeof(int);
    size_t need_r3 = head_fb + (size_t)E * sizeof(int4);

    if (ws_size >= need_r17 && nbins <= NBINS_MAX) {
        unsigned* hist  = (unsigned*)d_ws;
        unsigned* bsum  = reinterpret_cast<unsigned*>((char*)d_ws + hist_b);
        u32x2*    entry = reinterpret_cast<u32x2*>((char*)d_ws + hist_b + bsum_b);
        u32x4*    h8    = reinterpret_cast<u32x4*>((char*)d_ws + hist_b + bsum_b + ent_b);

        int n8 = N * (GCN_D / 8);                    // 1.6M groups of 8 floats
        int convBlocks = (n8 + block - 1) / block;   // 6250

        hist_convert_kernel<<<NBLK + convBlocks, block, 0, stream>>>(
            row, E, CH, nbins, hist,
            reinterpret_cast<const f32x4*>(embeds), n8, h8);

        scanA_kernel<<<SCAN_G, 256, 0, stream>>>(hist, M, chunk, bsum);
        scanC_kernel<<<SCAN_G, 256, 0, stream>>>(hist, M, chunk, bsum);

        scatter_kernel<<<NBLK, 1024, 0, stream>>>(
            row, col, edge_vals, E, CH, nbins, hist, entry);

        bin_reduce_kernel<<<nbins, 512, 0, stream>>>(
            hist, entry, reinterpret_cast<const __half2*>(h8), out, E, N, nbins);
    } else if (ws_size >= need_r3) {
        int*  head = (int*)d_ws;
        int4* node = reinterpret_cast<int4*>((char*)d_ws + head_fb);

        hipMemsetAsync(head, 0xFF, head_fb, stream);
        build_nodes_kernel<<<2048, block, 0, stream>>>(row, col, edge_vals,
                                                       E, head, node);

        long long threads = (long long)N * 64;
        int rblocks = (int)((threads + block - 1) / block);
        reduce_nodes_kernel<<<rblocks, block, 0, stream>>>(
            head, node, embeds, out, N);
    } else {
        hipMemsetAsync(d_out, 0, (size_t)out_size * sizeof(float), stream);
        long long total_threads = (long long)E * 32;
        long long grid = (total_threads + block - 1) / block;
        gcn_scatter_kernel<<<(unsigned)grid, block, 0, stream>>>(
            row, col, edge_vals, embeds, out, E);
        int n4 = out_size / 4;
        gcn_leaky_relu_kernel<<<(n4 + 255) / 256, 256, 0, stream>>>(out, n4);
    }
}

// Round 16
// 179.599 us; speedup vs baseline: 1.1241x; 1.1241x over previous
//
#include <hip/hip_runtime.h>
#include <hip/hip_fp16.h>

// GCN layer: out = leaky_relu( segment_sum(edge_vals[:,None] * embeds[col], row, N), 0.5 )
// E = 3.2M, N = 100000, D = 128, f32 in/out.
//
// R18: exact revert to R13 (179.8us -- the measured optimum of this structure).
// Config-space results (17 rounds): RPB=64 + CAP=3072 two-pass sort + cached
// entry loads + bin-major 1.6MB table + 1024-thr scatter + int4 loads +
// packed f32x2 FMA = minimum. Probed and worse:
//   - rank-fused sort @RPB=64 (R17: +8 VGPR -> occ 51%, CAP/3 -> 3x barriers, +23us)
//   - fine bins RPB=16 (R14-R16: -2us bin_reduce, +12us table traffic)
//   - occupancy 69->79% (R14: -2us; bin_reduce is gather-service-rate bound)
//   - LDS FP atomics (R6/R10: CAS loops, ~2.4ms), far-atomic chains (R2-R5),
//     half-wave gathers (R8), 6-entry reg-staging (R9), NT count/place (R12).
// bin_reduce floor: 819MB logical gathers at ~7.3TB/s cache+HBM service,
// VALU 36%, occ 69%, no pipe saturated -- the random-gather service rate is
// the wall. "other" = 66us with all passes coalesced/vectorized.
// Pipeline: hist(+fused f32->f16 convert) -> scanA -> scanC -> scatter -> bin_reduce.
// No global atomics, no FP atomics anywhere in the fast path.

#define GCN_D       128
#define LEAKY_SLOPE 0.5f
#define NBLK        256      // hist/scatter chunk partition of E
#define RPB         64       // rows per bin
#define RPB_SH      6
#define CAP         3072     // sorted entries per LDS chunk (24 KB)
#define NBINS_MAX   2048
#define SCAN_G      512      // scan pass-A/C blocks
#define NCHAIN_FB   4

typedef int      i32x4 __attribute__((ext_vector_type(4)));
typedef float    f32x2 __attribute__((ext_vector_type(2)));
typedef float    f32x4 __attribute__((ext_vector_type(4)));
typedef unsigned u32x2 __attribute__((ext_vector_type(2)));
typedef unsigned u32x4 __attribute__((ext_vector_type(4)));

__device__ inline unsigned pack_half2(float a, float b) {
    __half2 h = __floats2half2_rn(a, b);
    return *reinterpret_cast<unsigned*>(&h);
}

__device__ inline f32x2 h2_to_f2(__half2 h) {
    float2 f = __half22float2(h);
    f32x2 r; r.x = f.x; r.y = f.y;
    return r;
}

// ---------------- Pass 1: histogram + fused f32->f16 conversion ----------------

__global__ void hist_convert_kernel(const int* __restrict__ row,
                                    int E, int CH, int nbins,
                                    unsigned* __restrict__ hist,   // [nbins][NBLK]
                                    const f32x4* __restrict__ emb4,
                                    int n8,
                                    u32x4* __restrict__ h8) {
    __shared__ unsigned h[NBINS_MAX];
    if ((int)blockIdx.x < NBLK) {
        int b = blockIdx.x;
        for (int i = threadIdx.x; i < nbins; i += blockDim.x) h[i] = 0u;
        __syncthreads();
        int s = b * CH;
        int e = min(E, s + CH);
        int n = e - s;
        int g4 = n >> 2;                       // CH=12500: s is 4-aligned
        const i32x4* row4 = reinterpret_cast<const i32x4*>(row + s);
        for (int g = threadIdx.x; g < g4; g += blockDim.x) {
            i32x4 r4 = row4[g];
            atomicAdd(&h[r4.x >> RPB_SH], 1u);
            atomicAdd(&h[r4.y >> RPB_SH], 1u);
            atomicAdd(&h[r4.z >> RPB_SH], 1u);
            atomicAdd(&h[r4.w >> RPB_SH], 1u);
        }
        for (int i = s + (g4 << 2) + threadIdx.x; i < e; i += blockDim.x)
            atomicAdd(&h[row[i] >> RPB_SH], 1u);
        __syncthreads();
        for (int i = threadIdx.x; i < nbins; i += blockDim.x)
            hist[(long long)i * NBLK + b] = h[i];
    } else {
        int bid = (int)blockIdx.x - NBLK;
        int nb  = (int)gridDim.x - NBLK;
        int stride = nb * blockDim.x;
        for (int i = bid * blockDim.x + threadIdx.x; i < n8; i += stride) {
            f32x4 a  = __builtin_nontemporal_load(&emb4[2 * i]);
            f32x4 b2 = __builtin_nontemporal_load(&emb4[2 * i + 1]);
            u32x4 o;
            o.x = pack_half2(a.x, a.y);
            o.y = pack_half2(a.z, a.w);
            o.z = pack_half2(b2.x, b2.y);
            o.w = pack_half2(b2.z, b2.w);
            h8[i] = o;   // cache-allocate: gathers want this resident
        }
    }
}

// ---------------- Pass 2: 2-kernel multi-block exclusive scan ----------------

__global__ void __launch_bounds__(256)
scanA_kernel(const unsigned* __restrict__ data, int M, int chunk,
             unsigned* __restrict__ bsum) {
    __shared__ unsigned red[256];
    int b = blockIdx.x, t = threadIdx.x;
    long long s = (long long)b * chunk;
    unsigned acc = 0;
    for (int i = t; i < chunk; i += 256) {
        long long j = s + i;
        if (j < M) acc += data[j];
    }
    red[t] = acc;
    __syncthreads();
    for (int off = 128; off > 0; off >>= 1) {
        if (t < off) red[t] += red[t + off];
        __syncthreads();
    }
    if (t == 0) bsum[b] = red[0];
}

// scanC also reduces bsum[0..b) itself (raw block sums; <=SCAN_G u32).
__global__ void __launch_bounds__(256)
scanC_kernel(unsigned* __restrict__ data, int M, int chunk,
             const unsigned* __restrict__ bsum) {
    __shared__ unsigned pre[256];
    __shared__ unsigned basev;
    int b = blockIdx.x, t = threadIdx.x;

    unsigned acc0 = 0;
    for (int i = t; i < b; i += 256) acc0 += bsum[i];
    pre[t] = acc0;
    __syncthreads();
    for (int off = 128; off > 0; off >>= 1) {
        if (t < off) pre[t] += pre[t + off];
        __syncthreads();
    }
    if (t == 0) basev = pre[0];
    __syncthreads();

    long long s0 = (long long)b * chunk;
    long long s1 = s0 + chunk;
    int ept = (chunk + 255) / 256;
    long long ts = s0 + (long long)t * ept;

    unsigned acc = 0;
    for (int i = 0; i < ept; ++i) {
        long long j = ts + i;
        if (j < s1 && j < M) acc += data[j];
    }
    __syncthreads();
    pre[t] = acc;
    __syncthreads();
    for (int off = 1; off < 256; off <<= 1) {
        unsigned u = (t >= off) ? pre[t - off] : 0u;
        __syncthreads();
        pre[t] += u;
        __syncthreads();
    }
    unsigned run = basev + ((t == 0) ? 0u : pre[t - 1]);
    for (int i = 0; i < ept; ++i) {
        long long j = ts + i;
        if (j < s1 && j < M) {
            unsigned v = data[j];
            data[j] = run;
            run += v;
        }
    }
}

// ---------------- Pass 3: scatter entries at deterministic offsets ----------------

__global__ void __launch_bounds__(1024)
scatter_kernel(const int* __restrict__ row,
               const int* __restrict__ col,
               const float* __restrict__ val,
               int E, int CH, int nbins,
               const unsigned* __restrict__ scanned, // [nbins][NBLK]
               u32x2* __restrict__ entry) {
    __shared__ unsigned cur[NBINS_MAX];
    int b = blockIdx.x;
    for (int i = threadIdx.x; i < nbins; i += blockDim.x)
        cur[i] = scanned[(long long)i * NBLK + b];
    __syncthreads();

    int s = b * CH;
    int e = min(E, s + CH);
    int n = e - s;
    int g4 = n >> 2;

    const i32x4* row4 = reinterpret_cast<const i32x4*>(row + s);
    const i32x4* col4 = reinterpret_cast<const i32x4*>(col + s);
    const f32x4* val4 = reinterpret_cast<const f32x4*>(val + s);

    for (int g = threadIdx.x; g < g4; g += 1024) {
        i32x4 r4 = row4[g];
        i32x4 c4 = col4[g];
        f32x4 v4 = val4[g];
        #pragma unroll
        for (int k = 0; k < 4; ++k) {
            int r = r4[k];
            unsigned key = ((unsigned)(r & (RPB - 1)) << 17) | (unsigned)c4[k];
            unsigned pos = atomicAdd(&cur[r >> RPB_SH], 1u); // native u32 LDS atomic
            u32x2 q; q.x = key; q.y = __float_as_uint(v4[k]);
            entry[pos] = q;  // plain store: let L2 merge partial lines
        }
    }
    for (int i = s + (g4 << 2) + threadIdx.x; i < e; i += 1024) {
        int r = row[i];
        unsigned key = ((unsigned)(r & (RPB - 1)) << 17) | (unsigned)col[i];
        unsigned pos = atomicAdd(&cur[r >> RPB_SH], 1u);
        u32x2 q; q.x = key; q.y = __float_as_uint(val[i]);
        entry[pos] = q;
    }
}

// ---------------- Pass 4: per-bin LDS counting sort + packed register reduce ----------------

__global__ void __launch_bounds__(512)
bin_reduce_kernel(const unsigned* __restrict__ scanned,
                  const u32x2* __restrict__ entry,
                  const __half2* __restrict__ ebh,   // N*64 half2
                  float* __restrict__ out,
                  int E, int N, int nbins) {
    __shared__ u32x2    sorted[CAP];         // 24 KB
    __shared__ unsigned cnt[RPB];
    __shared__ unsigned offs[RPB];
    __shared__ unsigned cur[RPB];

    int b    = blockIdx.x;
    int tid  = threadIdx.x;
    int wave = tid >> 6;     // 0..7
    int lane = tid & 63;

    int seg0 = (int)scanned[(long long)b * NBLK];
    int seg1 = (b + 1 < nbins) ? (int)scanned[(long long)(b + 1) * NBLK] : E;

    f32x2 acc[8];
    #pragma unroll
    for (int j = 0; j < 8; ++j) { acc[j].x = 0.f; acc[j].y = 0.f; }

    for (int cs = seg0; cs < seg1; cs += CAP) {
        int n = min(CAP, seg1 - cs);

        if (tid < RPB) cnt[tid] = 0u;
        __syncthreads();

        // count (plain cached load -> place pass re-read is L2-hot)
        for (int i = tid; i < n; i += 512) {
            u32x2 q = entry[cs + i];
            atomicAdd(&cnt[q.x >> 17], 1u);   // native u32 LDS atomic
        }
        __syncthreads();

        // wave-parallel 64-lane exclusive prefix over cnt (RPB == 64)
        if (wave == 0) {
            unsigned c = cnt[lane];
            unsigned s = c;
            #pragma unroll
            for (int off = 1; off < 64; off <<= 1) {
                unsigned t = __shfl_up(s, off, 64);
                if (lane >= off) s += t;
            }
            offs[lane] = s - c;
            cur[lane]  = s - c;
        }
        __syncthreads();

        // place into row-sorted LDS order (L2-hot re-read)
        for (int i = tid; i < n; i += 512) {
            u32x2 q = entry[cs + i];
            unsigned pos = atomicAdd(&cur[q.x >> 17], 1u);
            sorted[pos] = q;
        }
        __syncthreads();

        // accumulate: each wave owns 8 rows; full-wave 256B gathers;
        // 8-deep main, 4-deep middle, 1-deep tail; packed f32x2 FMA.
        #pragma unroll
        for (int j = 0; j < 8; ++j) {
            int r  = (wave << 3) + j;
            int s  = (int)offs[r];
            int en = s + (int)cnt[r];
            int i  = s;
            for (; i + 8 <= en; i += 8) {
                u32x2 q0 = sorted[i],     q1 = sorted[i + 1];
                u32x2 q2 = sorted[i + 2], q3 = sorted[i + 3];
                u32x2 q4 = sorted[i + 4], q5 = sorted[i + 5];
                u32x2 q6 = sorted[i + 6], q7 = sorted[i + 7];
                __half2 m0 = ebh[(long long)(q0.x & 0x1FFFFu) * 64 + lane];
                __half2 m1 = ebh[(long long)(q1.x & 0x1FFFFu) * 64 + lane];
                __half2 m2 = ebh[(long long)(q2.x & 0x1FFFFu) * 64 + lane];
                __half2 m3 = ebh[(long long)(q3.x & 0x1FFFFu) * 64 + lane];
                __half2 m4 = ebh[(long long)(q4.x & 0x1FFFFu) * 64 + lane];
                __half2 m5 = ebh[(long long)(q5.x & 0x1FFFFu) * 64 + lane];
                __half2 m6 = ebh[(long long)(q6.x & 0x1FFFFu) * 64 + lane];
                __half2 m7 = ebh[(long long)(q7.x & 0x1FFFFu) * 64 + lane];
                f32x2 vv;
                vv.x = vv.y = __uint_as_float(q0.y); acc[j] += vv * h2_to_f2(m0);
                vv.x = vv.y = __uint_as_float(q1.y); acc[j] += vv * h2_to_f2(m1);
                vv.x = vv.y = __uint_as_float(q2.y); acc[j] += vv * h2_to_f2(m2);
                vv.x = vv.y = __uint_as_float(q3.y); acc[j] += vv * h2_to_f2(m3);
                vv.x = vv.y = __uint_as_float(q4.y); acc[j] += vv * h2_to_f2(m4);
                vv.x = vv.y = __uint_as_float(q5.y); acc[j] += vv * h2_to_f2(m5);
                vv.x = vv.y = __uint_as_float(q6.y); acc[j] += vv * h2_to_f2(m6);
                vv.x = vv.y = __uint_as_float(q7.y); acc[j] += vv * h2_to_f2(m7);
            }
            if (i + 4 <= en) {
                u32x2 q0 = sorted[i],     q1 = sorted[i + 1];
                u32x2 q2 = sorted[i + 2], q3 = sorted[i + 3];
                __half2 m0 = ebh[(long long)(q0.x & 0x1FFFFu) * 64 + lane];
                __half2 m1 = ebh[(long long)(q1.x & 0x1FFFFu) * 64 + lane];
                __half2 m2 = ebh[(long long)(q2.x & 0x1FFFFu) * 64 + lane];
                __half2 m3 = ebh[(long long)(q3.x & 0x1FFFFu) * 64 + lane];
                f32x2 vv;
                vv.x = vv.y = __uint_as_float(q0.y); acc[j] += vv * h2_to_f2(m0);
                vv.x = vv.y = __uint_as_float(q1.y); acc[j] += vv * h2_to_f2(m1);
                vv.x = vv.y = __uint_as_float(q2.y); acc[j] += vv * h2_to_f2(m2);
                vv.x = vv.y = __uint_as_float(q3.y); acc[j] += vv * h2_to_f2(m3);
                i += 4;
            }
            for (; i < en; ++i) {
                u32x2 qq = sorted[i];
                __half2 mm = ebh[(long long)(qq.x & 0x1FFFFu) * 64 + lane];
                f32x2 vv; vv.x = vv.y = __uint_as_float(qq.y);
                acc[j] += vv * h2_to_f2(mm);
            }
        }
        __syncthreads();
    }

    // fused leaky_relu + coalesced 512B stores (bin owns rows exclusively)
    int gr0 = b * RPB + (wave << 3);
    #pragma unroll
    for (int j = 0; j < 8; ++j) {
        int gr = gr0 + j;
        if (gr < N) {
            float x = acc[j].x, y = acc[j].y;
            x = x > 0.f ? x : LEAKY_SLOPE * x;
            y = y > 0.f ? y : LEAKY_SLOPE * y;
            f32x2 o; o.x = x; o.y = y;
            __builtin_nontemporal_store(
                o, reinterpret_cast<f32x2*>(out) + (long long)gr * 64 + lane);
        }
    }
}

// ---------------- R3 fallback: chains + f32 gather ----------------

__global__ void build_nodes_kernel(const int* __restrict__ row,
                                   const int* __restrict__ col,
                                   const float* __restrict__ val,
                                   int E,
                                   int* __restrict__ head,
                                   int4* __restrict__ node) {
    int stride = gridDim.x * blockDim.x;
    for (int i = blockIdx.x * blockDim.x + threadIdx.x; i < E; i += stride) {
        int   r = row[i];
        int   c = col[i];
        float v = val[i];
        int prev = atomicExch(&head[r * NCHAIN_FB + (i & (NCHAIN_FB - 1))], i);
        node[i] = make_int4(prev, c, __float_as_int(v), 0);
    }
}

__global__ void __launch_bounds__(256)
reduce_nodes_kernel(const int* __restrict__ head,
                    const int4* __restrict__ node,
                    const float* __restrict__ embeds,
                    float* __restrict__ out,
                    int N) {
    int wave = (int)((blockIdx.x * (long long)blockDim.x + threadIdx.x) >> 6);
    int lane = threadIdx.x & 63;
    if (wave >= N) return;

    const float2* eb = reinterpret_cast<const float2*>(embeds);
    int4 h = reinterpret_cast<const int4*>(head)[wave];
    int e0 = h.x, e1 = h.y, e2 = h.z, e3 = h.w;

    float ax = 0.f, ay = 0.f;

    while ((e0 & e1 & e2 & e3) != -1) {
        int i0 = e0 >= 0 ? e0 : 0;
        int i1 = e1 >= 0 ? e1 : 0;
        int i2 = e2 >= 0 ? e2 : 0;
        int i3 = e3 >= 0 ? e3 : 0;

        int4 n0 = node[i0];
        int4 n1 = node[i1];
        int4 n2 = node[i2];
        int4 n3 = node[i3];

        int c0 = e0 >= 0 ? n0.y : 0;
        int c1 = e1 >= 0 ? n1.y : 0;
        int c2 = e2 >= 0 ? n2.y : 0;
        int c3 = e3 >= 0 ? n3.y : 0;

        float2 m0 = eb[(long long)c0 * 64 + lane];
        float2 m1 = eb[(long long)c1 * 64 + lane];
        float2 m2 = eb[(long long)c2 * 64 + lane];
        float2 m3 = eb[(long long)c3 * 64 + lane];

        float v0 = e0 >= 0 ? __int_as_float(n0.z) : 0.f;
        float v1 = e1 >= 0 ? __int_as_float(n1.z) : 0.f;
        float v2 = e2 >= 0 ? __int_as_float(n2.z) : 0.f;
        float v3 = e3 >= 0 ? __int_as_float(n3.z) : 0.f;

        ax += v0 * m0.x; ay += v0 * m0.y;
        ax += v1 * m1.x; ay += v1 * m1.y;
        ax += v2 * m2.x; ay += v2 * m2.y;
        ax += v3 * m3.x; ay += v3 * m3.y;

        e0 = e0 >= 0 ? n0.x : -1;
        e1 = e1 >= 0 ? n1.x : -1;
        e2 = e2 >= 0 ? n2.x : -1;
        e3 = e3 >= 0 ? n3.x : -1;
    }

    ax = ax > 0.f ? ax : LEAKY_SLOPE * ax;
    ay = ay > 0.f ? ay : LEAKY_SLOPE * ay;
    reinterpret_cast<float2*>(out)[(long long)wave * 64 + lane] =
        make_float2(ax, ay);
}

// ---------------- R0 fallback: atomic scatter ----------------

__global__ void gcn_scatter_kernel(const int* __restrict__ row_idx,
                                   const int* __restrict__ col_idx,
                                   const float* __restrict__ vals,
                                   const float* __restrict__ embeds,
                                   float* __restrict__ out,
                                   int E) {
    long long tid = (long long)blockIdx.x * blockDim.x + threadIdx.x;
    long long e = tid >> 5;
    if (e >= E) return;
    int q = (int)(tid & 31);
    int row = row_idx[e];
    int col = col_idx[e];
    float v = vals[e];
    const float4* src =
        reinterpret_cast<const float4*>(embeds + (long long)col * GCN_D) + q;
    float4 m = *src;
    float* dst = out + (long long)row * GCN_D + (long long)q * 4;
    atomicAdd(dst + 0, v * m.x);
    atomicAdd(dst + 1, v * m.y);
    atomicAdd(dst + 2, v * m.z);
    atomicAdd(dst + 3, v * m.w);
}

__global__ void gcn_leaky_relu_kernel(float* __restrict__ out, int n4) {
    int i = blockIdx.x * blockDim.x + threadIdx.x;
    if (i >= n4) return;
    float4* p = reinterpret_cast<float4*>(out) + i;
    float4 x = *p;
    x.x = x.x > 0.f ? x.x : LEAKY_SLOPE * x.x;
    x.y = x.y > 0.f ? x.y : LEAKY_SLOPE * x.y;
    x.z = x.z > 0.f ? x.z : LEAKY_SLOPE * x.z;
    x.w = x.w > 0.f ? x.w : LEAKY_SLOPE * x.w;
    *p = x;
}

// ---------------------------------------------------------------------------

extern "C" void kernel_launch(void* const* d_in, const int* in_sizes, int n_in,
                              void* d_out, int out_size, void* d_ws, size_t ws_size,
                              hipStream_t stream) {
    const int*   edge_index = (const int*)d_in[0];   // (2, E) flat, int32
    const float* edge_vals  = (const float*)d_in[1]; // (E,)
    const float* embeds     = (const float*)d_in[2]; // (N, 128) f32
    float*       out        = (float*)d_out;         // (N, 128) f32

    const int E = in_sizes[1];
    const int N = out_size / GCN_D;                  // 100000
    const int* row = edge_index;
    const int* col = edge_index + E;

    const int block = 256;
    const int nbins = (N + RPB - 1) / RPB;           // 1563
    const int M     = nbins * NBLK;                  // 400128
    const int CH    = (E + NBLK - 1) / NBLK;         // 12500
    const int chunk = (M + SCAN_G - 1) / SCAN_G;     // 782

    // R18 ws layout: hist[M u32] | bsum[SCAN_G u32] | entry[E u32x2] | fp16 table
    size_t hist_b = (((size_t)M * sizeof(unsigned)) + 255) & ~(size_t)255;
    size_t bsum_b = (((size_t)SCAN_G * sizeof(unsigned)) + 255) & ~(size_t)255;
    size_t ent_b  = (((size_t)E * sizeof(u32x2)) + 255) & ~(size_t)255;
    size_t half_b = (size_t)N * GCN_D * sizeof(__half);
    size_t need_r18 = hist_b + bsum_b + ent_b + half_b;  // ~53 MB

    size_t head_fb = (size_t)N * NCHAIN_FB * sizeof(int);
    size_t need_r3 = head_fb + (size_t)E * sizeof(int4);

    if (ws_size >= need_r18 && nbins <= NBINS_MAX) {
        unsigned* hist  = (unsigned*)d_ws;
        unsigned* bsum  = reinterpret_cast<unsigned*>((char*)d_ws + hist_b);
        u32x2*    entry = reinterpret_cast<u32x2*>((char*)d_ws + hist_b + bsum_b);
        u32x4*    h8    = reinterpret_cast<u32x4*>((char*)d_ws + hist_b + bsum_b + ent_b);

        int n8 = N * (GCN_D / 8);                    // 1.6M groups of 8 floats
        int convBlocks = (n8 + block - 1) / block;   // 6250

        hist_convert_kernel<<<NBLK + convBlocks, block, 0, stream>>>(
            row, E, CH, nbins, hist,
            reinterpret_cast<const f32x4*>(embeds), n8, h8);

        scanA_kernel<<<SCAN_G, 256, 0, stream>>>(hist, M, chunk, bsum);
        scanC_kernel<<<SCAN_G, 256, 0, stream>>>(hist, M, chunk, bsum);

        scatter_kernel<<<NBLK, 1024, 0, stream>>>(
            row, col, edge_vals, E, CH, nbins, hist, entry);

        bin_reduce_kernel<<<nbins, 512, 0, stream>>>(
            hist, entry, reinterpret_cast<const __half2*>(h8), out, E, N, nbins);
    } else if (ws_size >= need_r3) {
        int*  head = (int*)d_ws;
        int4* node = reinterpret_cast<int4*>((char*)d_ws + head_fb);

        hipMemsetAsync(head, 0xFF, head_fb, stream);
        build_nodes_kernel<<<2048, block, 0, stream>>>(row, col, edge_vals,
                                                       E, head, node);

        long long threads = (long long)N * 64;
        int rblocks = (int)((threads + block - 1) / block);
        reduce_nodes_kernel<<<rblocks, block, 0, stream>>>(
            head, node, embeds, out, N);
    } else {
        hipMemsetAsync(d_out, 0, (size_t)out_size * sizeof(float), stream);
        long long total_threads = (long long)E * 32;
        long long grid = (total_threads + block - 1) / block;
        gcn_scatter_kernel<<<(unsigned)grid, block, 0, stream>>>(
            row, col, edge_vals, embeds, out, E);
        int n4 = out_size / 4;
        gcn_leaky_relu_kernel<<<(n4 + 255) / 256, 256, 0, stream>>>(out, n4);
    }
}